// Round 12
// baseline (142.031 us; speedup 1.0000x reference)
//
#include <hip/hip_runtime.h>

// Problem constants (B=2, S=2048, H=8, E=64).
// Harness passes f16 tensors upcast to FLOAT32 (in and out). Internally f16
// compute (lossless re-narrowing of f16-origin data), fp32 MFMA accumulation.
#define S_LEN 2048
#define NH    8
#define EMB   64
#define BM    128   // q rows per block: 4 waves x 2 q-tiles (W=2)
#define BN    64    // kv tile length
#define NKT   (S_LEN / BN)          // 32 kv tiles
#define NSPLIT 3    // KV splits: 16 bh x 16 qt x 3 = 768 blocks = 3/CU
#define PSTR  72    // padded LDS row stride for P (f16; 2-way bank alias = free)
#define M_INIT  (-1.0e4f)
#define EXP_CLAMP (-80.0f)

typedef _Float16 half8   __attribute__((ext_vector_type(8)));
typedef _Float16 half4   __attribute__((ext_vector_type(4)));
typedef float    float4_t __attribute__((ext_vector_type(4)));
typedef float    float8_t __attribute__((ext_vector_type(8)));

__device__ inline half8 cvt8(const float* p) {
    float8_t f = *reinterpret_cast<const float8_t*>(p);
    half8 h;
    #pragma unroll
    for (int j = 0; j < 8; ++j) h[j] = (_Float16)f[j];
    return h;
}

// async global->LDS, 16B per lane; LDS dest = uniform base + lane*16
__device__ inline void gload_lds16(const _Float16* g, _Float16* l) {
    __builtin_amdgcn_global_load_lds(
        (const __attribute__((address_space(1))) void*)g,
        (__attribute__((address_space(3))) void*)l, 16, 0, 0);
}

// ---------------------------------------------------------------------------
// Projection kernel, segment-selectable (seg passed as arg offset):
//   seg 0: Q -> Qout f32 [B,H,S,E], pre-scaled 0.125
//   seg 1: K -> KT8[bh][f/8][s][f%8] f16
//   seg 2: V -> VT8[bh][s/8][f][s%8] f16
// Launch A: grid 256, segBase 0 (Q only; q_in must be read before K/V
//           projections overwrite d_in[0]).
// Launch B: grid 512, segBase 1 (K and V).
// ---------------------------------------------------------------------------
__global__ __launch_bounds__(256) void proj_seg(
    const float* __restrict__ q_in, const float* __restrict__ k_in,
    const float* __restrict__ v_in,
    const float* __restrict__ Wq, const float* __restrict__ bq,
    const float* __restrict__ Wk, const float* __restrict__ bk,
    const float* __restrict__ Wv, const float* __restrict__ bv_,
    float* __restrict__ Qout, _Float16* __restrict__ KT8,
    _Float16* __restrict__ VT8, int segBase)
{
    const int seg = segBase + (blockIdx.x >> 8);
    const int bid = blockIdx.x & 255;
    const float* X    = (seg == 0) ? q_in : (seg == 1) ? k_in : v_in;
    const float* W    = (seg == 0) ? Wq   : (seg == 1) ? Wk   : Wv;
    const float* bias = (seg == 0) ? bq   : (seg == 1) ? bk   : bv_;

    const int tid  = threadIdx.x;
    const int lane = tid & 63;
    const int wave = tid >> 6;
    const int l15  = lane & 15;
    const int quad = lane >> 4;
    const int gwave = bid * 4 + wave;

    half8 wf[4][2];
    #pragma unroll
    for (int ft = 0; ft < 4; ++ft)
        #pragma unroll
        for (int ks = 0; ks < 2; ++ks)
            wf[ft][ks] = cvt8(W + (ft * 16 + l15) * 64 + ks * 32 + quad * 8);
    float bv[4];
    #pragma unroll
    for (int ft = 0; ft < 4; ++ft) bv[ft] = bias[ft * 16 + l15];

    #pragma unroll
    for (int rt2 = 0; rt2 < 2; ++rt2) {
        const int rt = gwave * 2 + rt2;
        const int arow = rt * 16 + l15;
        half8 xf[2];
        #pragma unroll
        for (int ks = 0; ks < 2; ++ks)
            xf[ks] = cvt8(X + (long)arow * 64 + ks * 32 + quad * 8);
        float4_t acc[4];
        #pragma unroll
        for (int ft = 0; ft < 4; ++ft) {
            acc[ft] = (float4_t){0.f, 0.f, 0.f, 0.f};
            #pragma unroll
            for (int ks = 0; ks < 2; ++ks)
                acc[ft] = __builtin_amdgcn_mfma_f32_16x16x32_f16(
                    xf[ks], wf[ft][ks], acc[ft], 0, 0, 0);
        }
        #pragma unroll
        for (int r = 0; r < 4; ++r) {
            const int row = rt * 16 + quad * 4 + r;     // (b*S+s)*H+h
            const int b = row >> 14;
            const int s = (row >> 3) & 2047;
            const int h = row & 7;
            const int bh = b * NH + h;
            #pragma unroll
            for (int ft = 0; ft < 4; ++ft) {
                const _Float16 v = (_Float16)(acc[ft][r] + bv[ft]);
                const int f = ft * 16 + l15;
                if (seg == 0)
                    Qout[((long)bh * S_LEN + s) * EMB + f] =
                        (float)(v * (_Float16)0.125f);
                else if (seg == 1)
                    KT8[(((long)bh * 8 + (f >> 3)) * S_LEN + s) * 8 + (f & 7)] = v;
                else
                    VT8[(((long)bh * 256 + (s >> 3)) * 64 + f) * 8 + (s & 7)] = v;
            }
        }
    }
}

// ---------------------------------------------------------------------------
// Flash attention partials, KV-split=3, S^T orientation, W=2: each wave owns
// TWO 16-row q-tiles, so every K/V LDS fragment read feeds 2 MFMAs (LDS b128
// reads per MFMA 1.125 -> 0.625 — attacks the measured LDS-pipe cap that made
// occupancy 23%->43% a no-op across R10/R11).
// ---------------------------------------------------------------------------
__global__ __launch_bounds__(256, 3) void attn_part(
    const _Float16* __restrict__ KT, const _Float16* __restrict__ VT,
    const float* __restrict__ Qbuf,
    _Float16* __restrict__ p0, _Float16* __restrict__ p1,
    _Float16* __restrict__ p2, float* __restrict__ stats)
{
    __shared__ __align__(16) _Float16 Kb[8 * 64 * 8];    // 8 KB [ec][tl][ej]
    __shared__ __align__(16) _Float16 Vb[8 * 64 * 8];    // 8 KB [tc][e][tj]
    __shared__ __align__(16) _Float16 Pl[4][32 * PSTR];  // 18 KB [g*16+q][t]

    const int tid  = threadIdx.x;
    const int lane = tid & 63;
    const int wave = tid >> 6;
    const int l15  = lane & 15;
    const int quad = lane >> 4;
    const int bx   = blockIdx.x;
    const int bh   = bx / (16 * NSPLIT);
    const int rem  = bx % (16 * NSPLIT);
    const int qt   = rem / NSPLIT;
    const int sp   = rem % NSPLIT;
    const long base = (long)bh * S_LEN * EMB;
    const int qrow0 = qt * BM + wave * 32;               // wave's 32 q-rows

    const _Float16* kg = KT + (long)bh * 8 * S_LEN * 8;  // head base in KT8

    half8 qf[2][2];   // B-frags: Q[q-row = qrow0+g*16+l15][e=ks*32+quad*8+j]
    #pragma unroll
    for (int g = 0; g < 2; ++g)
        #pragma unroll
        for (int ks = 0; ks < 2; ++ks)
            qf[g][ks] = cvt8(Qbuf + base + (long)(qrow0 + g * 16 + l15) * EMB
                             + ks * 32 + quad * 8);

    float4_t o[2][4];
    #pragma unroll
    for (int g = 0; g < 2; ++g)
        #pragma unroll
        for (int et = 0; et < 4; ++et) o[g][et] = (float4_t){0.f, 0.f, 0.f, 0.f};
    float m_run[2] = {M_INIT, M_INIT}, l_run[2] = {0.f, 0.f};

    const int kb = (sp * NKT) / NSPLIT, ke = ((sp + 1) * NKT) / NSPLIT; // 10/11/11
    for (int kt = kb; kt < ke; ++kt) {
        if (kt > kb) __syncthreads();     // prev-iter consumers done
        const int t0 = kt * BN;
        #pragma unroll
        for (int rr = 0; rr < 2; ++rr) {  // K tile: 512 units [ec][tl][ej]
            const int u = rr * 256 + tid;
            const int ec = u >> 6, tl = u & 63;
            gload_lds16(kg + ((long)ec * S_LEN + t0 + tl) * 8, Kb + u * 8);
        }
        const _Float16* vg = VT + ((long)bh * 256 + (t0 >> 3)) * 512;
        #pragma unroll
        for (int rr = 0; rr < 2; ++rr) {  // V tile: contiguous 8 KB
            const int u = rr * 256 + tid;
            gload_lds16(vg + u * 8, Vb + u * 8);
        }
        __syncthreads();                  // drains vmcnt -> tiles visible

        // S^T = K Q^T : each kf read feeds both q-tiles
        float4_t sacc[2][4];
        #pragma unroll
        for (int g = 0; g < 2; ++g)
            #pragma unroll
            for (int nt = 0; nt < 4; ++nt)
                sacc[g][nt] = (float4_t){0.f, 0.f, 0.f, 0.f};
        #pragma unroll
        for (int nt = 0; nt < 4; ++nt)
            #pragma unroll
            for (int ks = 0; ks < 2; ++ks) {
                half8 kf = *reinterpret_cast<const half8*>(   // A: K[m=t][e]
                    Kb + (ks * 4 + quad) * 512 + (nt * 16 + l15) * 8);
                sacc[0][nt] = __builtin_amdgcn_mfma_f32_16x16x32_f16(
                    kf, qf[0][ks], sacc[0][nt], 0, 0, 0);
                sacc[1][nt] = __builtin_amdgcn_mfma_f32_16x16x32_f16(
                    kf, qf[1][ks], sacc[1][nt], 0, 0, 0);
            }

        // softmax per q-tile (lane owns q-row l15 of each tile)
        _Float16* Pw = Pl[wave];
        #pragma unroll
        for (int g = 0; g < 2; ++g) {
            float mx = sacc[g][0][0];
            #pragma unroll
            for (int nt = 0; nt < 4; ++nt)
                #pragma unroll
                for (int r = 0; r < 4; ++r) mx = fmaxf(mx, sacc[g][nt][r]);
            mx = fmaxf(mx, __shfl_xor(mx, 16));
            mx = fmaxf(mx, __shfl_xor(mx, 32));
            const float mn = fmaxf(m_run[g], mx);
            const float alpha = __expf(fmaxf(m_run[g] - mn, EXP_CLAMP));
            m_run[g] = mn;
            float rsum = 0.f;
            #pragma unroll
            for (int nt = 0; nt < 4; ++nt) {
                half4 ph;
                #pragma unroll
                for (int r = 0; r < 4; ++r) {
                    const float p = __expf(sacc[g][nt][r] - m_run[g]);
                    rsum += p;
                    ph[r] = (_Float16)p;
                }
                *reinterpret_cast<half4*>(
                    &Pw[(g * 16 + l15) * PSTR + nt * 16 + quad * 4]) = ph;
            }
            rsum += __shfl_xor(rsum, 16);
            rsum += __shfl_xor(rsum, 32);
            l_run[g] = l_run[g] * alpha + rsum;
            #pragma unroll
            for (int r = 0; r < 4; ++r) {
                const float ar = __shfl(alpha, quad * 4 + r);
                #pragma unroll
                for (int et = 0; et < 4; ++et) o[g][et][r] *= ar;
            }
        }
        // no barrier: P write->read is intra-wave (compiler lgkmcnt)

        // O += P V : vf read once per (ts,et), feeds both q-tiles
        #pragma unroll
        for (int ts = 0; ts < 2; ++ts) {
            half8 vfr[4];
            #pragma unroll
            for (int et = 0; et < 4; ++et)
                vfr[et] = *reinterpret_cast<const half8*>(
                    Vb + (ts * 4 + quad) * 512 + (et * 16 + l15) * 8);
            #pragma unroll
            for (int g = 0; g < 2; ++g) {
                half8 pf = *reinterpret_cast<const half8*>(
                    &Pw[(g * 16 + l15) * PSTR + ts * 32 + quad * 8]);
                #pragma unroll
                for (int et = 0; et < 4; ++et)
                    o[g][et] = __builtin_amdgcn_mfma_f32_16x16x32_f16(
                        pf, vfr[et], o[g][et], 0, 0, 0);
            }
        }
    }

    // epilogue: normalized partial O-hat (f16) + (m,l) stats.
    _Float16* pp = (sp == 0) ? p0 : (sp == 1) ? p1 : p2;
    #pragma unroll
    for (int g = 0; g < 2; ++g)
        #pragma unroll
        for (int r = 0; r < 4; ++r) {
            const float lr = __shfl(l_run[g], quad * 4 + r);
            const float inv = 1.f / lr;
            const int row = qrow0 + g * 16 + quad * 4 + r;
            const int R = bh * S_LEN + row;              // 0..32767 global row
            #pragma unroll
            for (int et = 0; et < 4; ++et)
                pp[(long)R * EMB + et * 16 + l15] = (_Float16)(o[g][et][r] * inv);
        }
    if (lane < 16) {                                     // lane i owns q-row i
        #pragma unroll
        for (int g = 0; g < 2; ++g) {
            const int R = bh * S_LEN + qrow0 + g * 16 + lane;
            stats[sp * 32768 + R] = m_run[g];
            stats[(NSPLIT + sp) * 32768 + R] = l_run[g];
        }
    }
}

// ---------------------------------------------------------------------------
// Combine the 3 partials. O = sum w_i*Ohat_i, f16-round, f32 store.
// ---------------------------------------------------------------------------
__global__ __launch_bounds__(256) void attn_combine(
    const _Float16* __restrict__ p0, const _Float16* __restrict__ p1,
    const _Float16* __restrict__ p2, const float* __restrict__ stats,
    float* __restrict__ out)
{
    const int gid = blockIdx.x * 256 + threadIdx.x;      // 131072 threads
    const int R  = gid >> 2;
    const int c0 = (gid & 3) * 16;
    const float m0 = stats[R], m1 = stats[32768 + R], m2 = stats[2 * 32768 + R];
    const float l0 = stats[3 * 32768 + R], l1 = stats[4 * 32768 + R],
                l2 = stats[5 * 32768 + R];
    const float M = fmaxf(fmaxf(m0, m1), m2);
    float w0 = l0 * __expf(fmaxf(m0 - M, EXP_CLAMP));
    float w1 = l1 * __expf(fmaxf(m1 - M, EXP_CLAMP));
    float w2 = l2 * __expf(fmaxf(m2 - M, EXP_CLAMP));
    const float rinv = 1.f / (w0 + w1 + w2);
    w0 *= rinv; w1 *= rinv; w2 *= rinv;
    const long i0 = (long)R * EMB + c0;
    #pragma unroll
    for (int h = 0; h < 2; ++h) {
        half8 a = *reinterpret_cast<const half8*>(p0 + i0 + h * 8);
        half8 b = *reinterpret_cast<const half8*>(p1 + i0 + h * 8);
        half8 c = *reinterpret_cast<const half8*>(p2 + i0 + h * 8);
        #pragma unroll
        for (int j = 0; j < 8; ++j)
            out[i0 + h * 8 + j] = (float)(_Float16)(
                w0 * (float)a[j] + w1 * (float)b[j] + w2 * (float)c[j]);
    }
}

// ---------------------------------------------------------------------------
// 4 launches. Buffer plan (no d_ws; stream-ordered liveness):
//   L1 proj_seg(segBase=0, grid 256): Q: d_in[0] -> d_out (f32, pre-scaled)
//   L2 proj_seg(segBase=1, grid 512): K -> KT8 = d_in[0][0,4MB);
//                                     V -> VT8 = d_in[0][4,8MB)  (q_in dead)
//   L3 attn_part: reads KT8/VT8/d_out; p0,p1 -> d_in[2] (v_in dead),
//                 p2 -> d_in[1][0,4MB) (k_in dead), stats -> d_in[1][4,4.75MB)
//   L4 combine -> d_out (Q dead)
// ---------------------------------------------------------------------------
extern "C" void kernel_launch(void* const* d_in, const int* in_sizes, int n_in,
                              void* d_out, int out_size, void* d_ws, size_t ws_size,
                              hipStream_t stream) {
    const float* q_in = (const float*)d_in[0];
    const float* k_in = (const float*)d_in[1];
    const float* v_in = (const float*)d_in[2];
    const float* Wq   = (const float*)d_in[3];
    const float* bq   = (const float*)d_in[4];
    const float* Wk   = (const float*)d_in[5];
    const float* bk   = (const float*)d_in[6];
    const float* Wv   = (const float*)d_in[7];
    const float* bv   = (const float*)d_in[8];
    float* out = (float*)d_out;

    _Float16* KT8   = (_Float16*)d_in[0];
    _Float16* VT8   = (_Float16*)((char*)d_in[0] + (4u << 20));
    _Float16* part0 = (_Float16*)d_in[2];
    _Float16* part1 = part0 + (long)2 * 1024 * 1024;           // +4 MB
    _Float16* part2 = (_Float16*)d_in[1];
    float*    stats = (float*)((char*)d_in[1] + (4u << 20));

    proj_seg<<<256, 256, 0, stream>>>(q_in, k_in, v_in, Wq, bq, Wk, bk,
                                      Wv, bv, out, KT8, VT8, 0);
    proj_seg<<<512, 256, 0, stream>>>(q_in, k_in, v_in, Wq, bq, Wk, bk,
                                      Wv, bv, out, KT8, VT8, 1);
    attn_part<<<16 * 16 * NSPLIT, 256, 0, stream>>>(KT8, VT8, out,
                                                    part0, part1, part2, stats);
    attn_combine<<<512, 256, 0, stream>>>(part0, part1, part2, stats, out);
}